// Round 5
// baseline (586.980 us; speedup 1.0000x reference)
//
#include <hip/hip_runtime.h>

// Problem constants (from reference): D=4, J=256, K=512, H=512, B=1024
#define J_ 256
#define K_ 512
#define H_ 512
#define B_ 1024

typedef float f32x4 __attribute__((ext_vector_type(4)));
typedef unsigned int u32x4 __attribute__((ext_vector_type(4)));
typedef unsigned short u16x4 __attribute__((ext_vector_type(4)));
typedef unsigned short u16x8 __attribute__((ext_vector_type(8)));
typedef __bf16 bf16x8 __attribute__((ext_vector_type(8)));

// f32 -> bf16 round-to-nearest-even (manual; inputs are finite)
__device__ __forceinline__ unsigned short f2bf(float f) {
    unsigned int u = __float_as_uint(f);
    u += 0x7fffu + ((u >> 16) & 1u);
    return (unsigned short)(u >> 16);
}

// async global->LDS, 16B per lane; LDS dest is wave-uniform base + lane*16
__device__ __forceinline__ void gload_lds16(const void* g, void* l) {
    __builtin_amdgcn_global_load_lds(
        (const __attribute__((address_space(1))) unsigned int*)g,
        (__attribute__((address_space(3))) unsigned int*)l, 16, 0, 0);
}

// Prep: x f32 -> bf16 into ws; init out: mu[b,j] = b1[j]; logvar tail.
__global__ __launch_bounds__(256) void prep_kernel(
    const float* __restrict__ x, const float* __restrict__ b1,
    const float* __restrict__ logvar, unsigned short* __restrict__ xbf,
    float* __restrict__ out) {
    int t = blockIdx.x * 256 + threadIdx.x;
    {
        f32x4 v = *(const f32x4*)(x + (size_t)t * 4);
        u16x4 o;
        o[0] = f2bf(v[0]); o[1] = f2bf(v[1]); o[2] = f2bf(v[2]); o[3] = f2bf(v[3]);
        *(u16x4*)(xbf + (size_t)t * 4) = o;
    }
    if (t < (B_ * J_) / 4) {
        int b = t >> 6;
        int j4 = (t & 63) << 2;
        f32x4 bb = *(const f32x4*)(b1 + j4);
        *(f32x4*)(out + ((size_t)b << 8) + j4) = bb;
    }
    if (t < 4) out[B_ * J_ + t] = logvar[t];
}

// W0' = bf16(W0 * wi), memory-bound pass. 8 elems/thread, 32768 blocks x 256.
__global__ __launch_bounds__(256) void wprep_kernel(
    const float* __restrict__ W0, const float* __restrict__ wmask,
    const int* __restrict__ ip, unsigned short* __restrict__ w0p) {
    size_t t = (size_t)blockIdx.x * 256 + threadIdx.x;
    size_t e = t * 8;
    int j = (int)(e >> 18);               // H*K = 262144 elems per j
    int k = (int)(e & (K_ - 1));
    const float* wi = wmask + ((size_t)ip[0] * J_ + j) * K_ + k;
    f32x4 s0 = *(const f32x4*)wi;
    f32x4 s1 = *(const f32x4*)(wi + 4);
    f32x4 a0 = *(const f32x4*)(W0 + e);
    f32x4 a1 = *(const f32x4*)(W0 + e + 4);
    a0 *= s0; a1 *= s1;
    u16x8 o;
    #pragma unroll
    for (int q = 0; q < 4; ++q) { o[q] = f2bf(a0[q]); o[q + 4] = f2bf(a1[q]); }
    *(u16x8*)(w0p + e) = o;
}

// Pipelined grouped GEMM: tile 256(M)x128(N), BK=64, 512 thr (8 waves, 4Mx2N),
// triple-buffered LDS (3 x 48KB), counted vmcnt (never 0 in steady state).
// Grid 4096 = j(256) x mb(4) x nb(4); all 16 blocks of a j on one XCD.
__global__ __launch_bounds__(512, 1) void enc_kernel(
    const unsigned short* __restrict__ xbf,
    const unsigned short* __restrict__ w0p,
    const float* __restrict__ b0,
    const float* __restrict__ W1,
    float* __restrict__ out) {
    // per buffer: A = 256 rows x 128B (32KB), B = 128 rows x 128B (16KB)
    __shared__ unsigned char lds[3 * 49152];

    int p = blockIdx.x;
    int xcd = p & 7;
    int q = p >> 3;
    int j = (xcd << 5) + (q >> 4);
    int inner = q & 15;
    int m0 = (inner >> 2) << 8;      // 0,256,512,768
    int h0 = (inner & 3) << 7;       // 0,128,256,384

    int tid = threadIdx.x;
    int lane = tid & 63;
    int wv = tid >> 6;               // 0..7
    int wmv = wv >> 1;               // M-wave 0..3 (64 rows each)
    int wnv = wv & 1;                // N-wave 0..1 (64 cols each)
    int lr = lane & 15, lg = lane >> 4;

    int lrow = lane >> 3;            // 0..7
    int lch = lane & 7;
    int sch = ((lch ^ lrow) << 3);   // pre-swizzled source chunk (elems)

    // staging bases: each gload instruction covers 8 rows per wave (x8 waves = 64)
    const unsigned short* aSrc = xbf + (size_t)(m0 + wv * 8 + lrow) * K_ + sch;
    const unsigned short* bSrc = w0p + ((size_t)j * H_ + h0 + wv * 8 + lrow) * K_ + sch;
    unsigned char* ldsAW = lds + wv * 1024;           // + bi*49152 + ii*8192
    unsigned char* ldsBW = lds + 32768 + wv * 1024;

    f32x4 acc[4][4] = {};            // wave tile 64(m) x 64(h)

#define VMW(n) do { asm volatile("s_waitcnt vmcnt(" #n ")" ::: "memory"); \
                    __builtin_amdgcn_sched_barrier(0); } while (0)
#define BAR() do { __builtin_amdgcn_s_barrier(); \
                   __builtin_amdgcn_sched_barrier(0); } while (0)

#define STAGE(bi, ks) do { \
    _Pragma("unroll") for (int ii = 0; ii < 4; ++ii) \
        gload_lds16(aSrc + (size_t)ii * 64 * K_ + (ks) * 64, \
                    ldsAW + (bi) * 49152 + ii * 8192); \
    _Pragma("unroll") for (int ii = 0; ii < 2; ++ii) \
        gload_lds16(bSrc + (size_t)ii * 64 * K_ + (ks) * 64, \
                    ldsBW + (bi) * 49152 + ii * 8192); \
    } while (0)

#define COMPUTE(bi) do { \
    const unsigned char* LA = lds + (bi) * 49152; \
    const unsigned char* LB = LA + 32768; \
    _Pragma("unroll") for (int kf = 0; kf < 2; ++kf) { \
        bf16x8 af[4], bv[4]; \
        int colk = (kf << 6) + (lg << 4); \
        _Pragma("unroll") for (int mf = 0; mf < 4; ++mf) { \
            int r = (wmv << 6) + (mf << 4) + lr; \
            af[mf] = *(const bf16x8*)(LA + r * 128 + (colk ^ ((r & 7) << 4))); \
        } \
        _Pragma("unroll") for (int nf = 0; nf < 4; ++nf) { \
            int hr = (wnv << 6) + (nf << 4) + lr; \
            bv[nf] = *(const bf16x8*)(LB + hr * 128 + (colk ^ ((hr & 7) << 4))); \
        } \
        __builtin_amdgcn_s_setprio(1); \
        _Pragma("unroll") for (int mf = 0; mf < 4; ++mf) \
            _Pragma("unroll") for (int nf = 0; nf < 4; ++nf) \
                acc[mf][nf] = __builtin_amdgcn_mfma_f32_16x16x32_bf16( \
                    af[mf], bv[nf], acc[mf][nf], 0, 0, 0); \
        __builtin_amdgcn_s_setprio(0); \
    } } while (0)

    // Pipeline: stage(ks+2) -> vmcnt(12) [waits only 2-step-old loads] -> bar
    // -> compute(ks) -> bar.  Stage target (ks+2)%3 == (ks-1)%3, whose readers
    // all passed the previous end-of-step barrier => race-free.
    STAGE(0, 0); STAGE(1, 1);
    STAGE(2, 2); VMW(12); BAR(); COMPUTE(0); BAR();
    STAGE(0, 3); VMW(12); BAR(); COMPUTE(1); BAR();
    STAGE(1, 4); VMW(12); BAR(); COMPUTE(2); BAR();
    STAGE(2, 5); VMW(12); BAR(); COMPUTE(0); BAR();
    STAGE(0, 6); VMW(12); BAR(); COMPUTE(1); BAR();
    STAGE(1, 7); VMW(12); BAR(); COMPUTE(2); BAR();
                 VMW(6);  BAR(); COMPUTE(0); BAR();
                 VMW(0);  BAR(); COMPUTE(1);

    // fused epilogue: h = leaky(acc + b0); partial mu = h . W1 (reduce 64 cols)
    float b0v[4], w1v[4];
    #pragma unroll
    for (int nf = 0; nf < 4; ++nf) {
        int col = h0 + (wnv << 6) + (nf << 4) + lr;
        b0v[nf] = b0[(size_t)j * H_ + col];
        w1v[nf] = W1[(size_t)j * H_ + col];
    }
    #pragma unroll
    for (int mf = 0; mf < 4; ++mf) {
        #pragma unroll
        for (int rg = 0; rg < 4; ++rg) {
            float ps = 0.f;
            #pragma unroll
            for (int nf = 0; nf < 4; ++nf) {
                float hv = acc[mf][nf][rg] + b0v[nf];  // C/D: col=lr, row=lg*4+rg
                hv = hv > 0.f ? hv : 0.01f * hv;
                ps += hv * w1v[nf];
            }
            ps += __shfl_xor(ps, 1);
            ps += __shfl_xor(ps, 2);
            ps += __shfl_xor(ps, 4);
            ps += __shfl_xor(ps, 8);
            if (lr == 0) {
                int row = m0 + (wmv << 6) + (mf << 4) + (lg << 2) + rg;
                atomicAdd(out + (size_t)row * J_ + j, ps);
            }
        }
    }
#undef VMW
#undef BAR
#undef STAGE
#undef COMPUTE
}

// Fallback (ws too small): on-the-fly mask*W0 cvt staging (round-2 proven).
__global__ __launch_bounds__(256, 2) void enc_kernel_fb(
    const unsigned short* __restrict__ xbf,
    const float* __restrict__ W0,
    const float* __restrict__ wmask,
    const int* __restrict__ ip,
    const float* __restrict__ b0,
    const float* __restrict__ W1,
    float* __restrict__ out) {
    __shared__ unsigned char ldsA[128 * 128];
    __shared__ unsigned char ldsB[128 * 128];

    int p = blockIdx.x;
    int xcd = p & 7;
    int q = p >> 3;
    int j = (xcd << 5) + (q >> 5);
    int inner = q & 31;
    int m0 = (inner >> 2) << 7;
    int h0 = (inner & 3) << 7;

    int i = ip[0];
    const float* w0j = W0 + (size_t)j * (H_ * K_);
    const float* wij = wmask + ((size_t)i * J_ + j) * K_;

    int tid = threadIdx.x;
    int lane = tid & 63;
    int wv = tid >> 6;
    int wm = wv >> 1, wn = wv & 1;
    int lr = lane & 15, lg = lane >> 4;
    int srow0 = tid >> 3;
    int c = tid & 7;

    f32x4 acc[4][4] = {};

    for (int ks = 0; ks < K_ / 64; ++ks) {
        int k0 = ks * 64;
        #pragma unroll
        for (int it = 0; it < 4; ++it) {
            int r = srow0 + it * 32;
            u32x4 v = *(const u32x4*)(xbf + (size_t)(m0 + r) * K_ + k0 + c * 8);
            *(u32x4*)(ldsA + r * 128 + ((c * 16) ^ ((r & 7) << 4))) = v;
        }
        f32x4 s0 = *(const f32x4*)(wij + k0 + c * 8);
        f32x4 s1 = *(const f32x4*)(wij + k0 + c * 8 + 4);
        #pragma unroll
        for (int it = 0; it < 4; ++it) {
            int hr = srow0 + it * 32;
            const float* src = w0j + (size_t)(h0 + hr) * K_ + k0 + c * 8;
            f32x4 a0 = *(const f32x4*)(src);
            f32x4 a1 = *(const f32x4*)(src + 4);
            a0 *= s0; a1 *= s1;
            u16x8 bvv;
            #pragma unroll
            for (int e = 0; e < 4; ++e) { bvv[e] = f2bf(a0[e]); bvv[e + 4] = f2bf(a1[e]); }
            *(u16x8*)(ldsB + hr * 128 + ((c * 16) ^ ((hr & 7) << 4))) = bvv;
        }
        __syncthreads();
        #pragma unroll
        for (int kf = 0; kf < 2; ++kf) {
            bf16x8 af[4], bfr[4];
            #pragma unroll
            for (int mf = 0; mf < 4; ++mf) {
                int r = (wm << 6) + (mf << 4) + lr;
                af[mf] = *(const bf16x8*)(ldsA + r * 128 +
                          (((kf << 6) + (lg << 4)) ^ ((r & 7) << 4)));
            }
            #pragma unroll
            for (int nf = 0; nf < 4; ++nf) {
                int hrw = (wn << 6) + (nf << 4) + lr;
                bfr[nf] = *(const bf16x8*)(ldsB + hrw * 128 +
                          (((kf << 6) + (lg << 4)) ^ ((hrw & 7) << 4)));
            }
            #pragma unroll
            for (int mf = 0; mf < 4; ++mf)
                #pragma unroll
                for (int nf = 0; nf < 4; ++nf)
                    acc[mf][nf] = __builtin_amdgcn_mfma_f32_16x16x32_bf16(
                        af[mf], bfr[nf], acc[mf][nf], 0, 0, 0);
        }
        __syncthreads();
    }

    float b0v[4], w1v[4];
    #pragma unroll
    for (int nf = 0; nf < 4; ++nf) {
        int h = h0 + (wn << 6) + (nf << 4) + lr;
        b0v[nf] = b0[(size_t)j * H_ + h];
        w1v[nf] = W1[(size_t)j * H_ + h];
    }
    #pragma unroll
    for (int mf = 0; mf < 4; ++mf) {
        #pragma unroll
        for (int rg = 0; rg < 4; ++rg) {
            float ps = 0.f;
            #pragma unroll
            for (int nf = 0; nf < 4; ++nf) {
                float hv = acc[mf][nf][rg] + b0v[nf];
                hv = hv > 0.f ? hv : 0.01f * hv;
                ps += hv * w1v[nf];
            }
            ps += __shfl_xor(ps, 1);
            ps += __shfl_xor(ps, 2);
            ps += __shfl_xor(ps, 4);
            ps += __shfl_xor(ps, 8);
            if (lr == 0) {
                int row = m0 + (wm << 6) + (mf << 4) + (lg << 2) + rg;
                atomicAdd(out + (size_t)row * J_ + j, ps);
            }
        }
    }
}

extern "C" void kernel_launch(void* const* d_in, const int* in_sizes, int n_in,
                              void* d_out, int out_size, void* d_ws, size_t ws_size,
                              hipStream_t stream) {
    const float* x      = (const float*)d_in[0];
    const int*   ip     = (const int*)d_in[1];
    const float* wmask  = (const float*)d_in[2];
    const float* W0     = (const float*)d_in[3];
    const float* b0     = (const float*)d_in[4];
    const float* W1     = (const float*)d_in[5];
    const float* b1     = (const float*)d_in[6];
    const float* logvar = (const float*)d_in[7];
    float* out = (float*)d_out;
    unsigned short* xbf = (unsigned short*)d_ws;          // 1 MB
    const size_t xbf_elems = (size_t)B_ * K_;
    const size_t w0p_bytes = (size_t)J_ * H_ * K_ * 2;    // 134.2 MB
    const size_t need = xbf_elems * 2 + w0p_bytes;

    prep_kernel<<<512, 256, 0, stream>>>(x, b1, logvar, xbf, out);
    if (ws_size >= need) {
        unsigned short* w0p = xbf + xbf_elems;
        wprep_kernel<<<32768, 256, 0, stream>>>(W0, wmask, ip, w0p);
        enc_kernel<<<4096, 512, 0, stream>>>(xbf, w0p, b0, W1, out);
    } else {
        enc_kernel_fb<<<8192, 256, 0, stream>>>(xbf, W0, wmask, ip, b0, W1, out);
    }
}